// Round 7
// baseline (1291.890 us; speedup 1.0000x reference)
//
#include <hip/hip_runtime.h>

#define DD 256
#define NVAR 20000
#define NFAC 40000
#define NEDGE 320000
#define NGRAPH 64

#define NBF ((NFAC + 255) / 256)   // 157
#define NBV ((NVAR + 255) / 256)   // 79

typedef __bf16 bf16_t;
typedef bf16_t bf16x8 __attribute__((ext_vector_type(8)));
typedef bf16_t bf16x4 __attribute__((ext_vector_type(4)));
typedef float f32x4 __attribute__((ext_vector_type(4)));

#define GBM 128
#define GBN 128
#define GBK 32
#define LDK 40   // padded k-stride (bf16 elems) for LDS tiles

// ordered-uint encoding of float for atomicMax (monotone: a<b <=> enc(a)<enc(b))
__device__ __forceinline__ unsigned encf(float f) {
    int i = __float_as_int(f);
    return (i >= 0) ? ((unsigned)i + 0x80000000u) : (unsigned)(~i);
}
__device__ __forceinline__ float decf(unsigned u) {
    int i = (u >= 0x80000000u) ? (int)(u - 0x80000000u) : ~(int)u;
    return __int_as_float(i);
}

// ---------------- MFMA GEMM (combine / att) ----------------
// C[M x 256] = (HASRES ? res : 0) + act( A1@W(kOff1) + (HASA2 ? A2@W(kOff2) : 0) + bias )
template<bool RELU, bool HASA2, bool HASRES, bool A2BF, bool OUTBF>
__global__ __launch_bounds__(256)
void mgemm_k(const float* __restrict__ A1, const void* __restrict__ A2v,
             const bf16_t* __restrict__ Wt, int wtStride, int kOff1, int kOff2,
             const float* __restrict__ bias, const float* __restrict__ res,
             void* __restrict__ Cv, int M)
{
    __shared__ bf16_t sA[GBM * LDK];
    __shared__ bf16_t sB[GBN * LDK];

    const int tid = threadIdx.x;
    const int bm = blockIdx.x * GBM;
    const int bn = blockIdx.y * GBN;

    const int w  = tid >> 6;
    const int l  = tid & 63;
    const int wr = w >> 1;
    const int wc = w & 1;
    const int lm = l & 15;
    const int kg = l >> 4;

    const int srow = tid >> 1;
    const int shalf = (tid & 1) * 16;

    f32x4 acc[4][4];
#pragma unroll
    for (int i = 0; i < 4; ++i)
#pragma unroll
        for (int j = 0; j < 4; ++j) acc[i][j] = (f32x4)0.f;

    const int nops = HASA2 ? 2 : 1;
    for (int op = 0; op < nops; ++op) {
        const int kOff = op ? kOff2 : kOff1;
        for (int k0 = 0; k0 < DD; k0 += GBK) {
            {
                const int grow = bm + srow;
                bf16x8* d = (bf16x8*)&sA[srow * LDK + shalf];
                if (op == 1 && A2BF) {
                    const bf16_t* A2b = (const bf16_t*)A2v;
                    if (grow < M) {
                        const bf16x8* s = (const bf16x8*)(A2b + (size_t)grow * DD + k0 + shalf);
                        d[0] = s[0]; d[1] = s[1];
                    } else {
                        d[0] = (bf16x8)(bf16_t)0.f; d[1] = (bf16x8)(bf16_t)0.f;
                    }
                } else {
                    const float* Aop = op ? (const float*)A2v : A1;
                    bf16_t tmp[16];
                    if (grow < M) {
                        const float4* p = (const float4*)(Aop + (size_t)grow * DD + k0 + shalf);
                        float4 x0 = p[0], x1 = p[1], x2 = p[2], x3 = p[3];
                        tmp[0]=(bf16_t)x0.x; tmp[1]=(bf16_t)x0.y; tmp[2]=(bf16_t)x0.z; tmp[3]=(bf16_t)x0.w;
                        tmp[4]=(bf16_t)x1.x; tmp[5]=(bf16_t)x1.y; tmp[6]=(bf16_t)x1.z; tmp[7]=(bf16_t)x1.w;
                        tmp[8]=(bf16_t)x2.x; tmp[9]=(bf16_t)x2.y; tmp[10]=(bf16_t)x2.z; tmp[11]=(bf16_t)x2.w;
                        tmp[12]=(bf16_t)x3.x; tmp[13]=(bf16_t)x3.y; tmp[14]=(bf16_t)x3.z; tmp[15]=(bf16_t)x3.w;
                    } else {
#pragma unroll
                        for (int j = 0; j < 16; ++j) tmp[j] = (bf16_t)0.f;
                    }
                    d[0] = *(bf16x8*)&tmp[0];
                    d[1] = *(bf16x8*)&tmp[8];
                }
            }
            {
                const bf16x8* s = (const bf16x8*)(Wt + (size_t)(bn + srow) * wtStride + kOff + k0 + shalf);
                bf16x8* d = (bf16x8*)&sB[srow * LDK + shalf];
                d[0] = s[0];
                d[1] = s[1];
            }
            __syncthreads();
            bf16x8 af[4], bfr[4];
#pragma unroll
            for (int i = 0; i < 4; ++i)
                af[i] = *(bf16x8*)&sA[(wr * 64 + i * 16 + lm) * LDK + kg * 8];
#pragma unroll
            for (int j = 0; j < 4; ++j)
                bfr[j] = *(bf16x8*)&sB[(wc * 64 + j * 16 + lm) * LDK + kg * 8];
#pragma unroll
            for (int i = 0; i < 4; ++i)
#pragma unroll
                for (int j = 0; j < 4; ++j)
                    acc[i][j] = __builtin_amdgcn_mfma_f32_16x16x32_bf16(af[i], bfr[j], acc[i][j], 0, 0, 0);
            __syncthreads();
        }
    }

#pragma unroll
    for (int j = 0; j < 4; ++j) {
        const int col = bn + wc * 64 + j * 16 + lm;
        const float bv = bias ? bias[col] : 0.f;
#pragma unroll
        for (int i = 0; i < 4; ++i) {
            const int rbase = bm + wr * 64 + i * 16 + kg * 4;
#pragma unroll
            for (int r = 0; r < 4; ++r) {
                const int rw = rbase + r;
                if (rw < M) {
                    float v = acc[i][j][r] + bv;
                    if (RELU) v = fmaxf(v, 0.f);
                    if (HASRES) v += res[(size_t)rw * DD + col];
                    if (OUTBF) ((bf16_t*)Cv)[(size_t)rw * DD + col] = (bf16_t)v;
                    else       ((float*)Cv)[(size_t)rw * DD + col] = v;
                }
            }
        }
    }
}

// ---------------- dual P-GEMM: two independent M-row sets, same Wt, bf16 out ----------------
__global__ __launch_bounds__(256)
void pgemm_k(const float* __restrict__ Aa, const float* __restrict__ biasA, int kOffA,
             bf16_t* __restrict__ Ca, int Ma, int gridXA,
             const float* __restrict__ Ab, const float* __restrict__ biasB, int kOffB,
             bf16_t* __restrict__ Cb, int Mb,
             const bf16_t* __restrict__ Wt, int wtStride)
{
    __shared__ bf16_t sA[GBM * LDK];
    __shared__ bf16_t sB[GBN * LDK];

    const int tid = threadIdx.x;
    const bool partB = (int)blockIdx.x >= gridXA;
    const int bx = partB ? (blockIdx.x - gridXA) : blockIdx.x;
    const float* A = partB ? Ab : Aa;
    const float* bias = partB ? biasB : biasA;
    const int kOff = partB ? kOffB : kOffA;
    bf16_t* C = partB ? Cb : Ca;
    const int M = partB ? Mb : Ma;

    const int bm = bx * GBM;
    const int bn = blockIdx.y * GBN;

    const int w  = tid >> 6;
    const int l  = tid & 63;
    const int wr = w >> 1;
    const int wc = w & 1;
    const int lm = l & 15;
    const int kg = l >> 4;

    const int srow = tid >> 1;
    const int shalf = (tid & 1) * 16;

    f32x4 acc[4][4];
#pragma unroll
    for (int i = 0; i < 4; ++i)
#pragma unroll
        for (int j = 0; j < 4; ++j) acc[i][j] = (f32x4)0.f;

    for (int k0 = 0; k0 < DD; k0 += GBK) {
        {
            const int grow = bm + srow;
            bf16_t tmp[16];
            if (grow < M) {
                const float4* p = (const float4*)(A + (size_t)grow * DD + k0 + shalf);
                float4 x0 = p[0], x1 = p[1], x2 = p[2], x3 = p[3];
                tmp[0]=(bf16_t)x0.x; tmp[1]=(bf16_t)x0.y; tmp[2]=(bf16_t)x0.z; tmp[3]=(bf16_t)x0.w;
                tmp[4]=(bf16_t)x1.x; tmp[5]=(bf16_t)x1.y; tmp[6]=(bf16_t)x1.z; tmp[7]=(bf16_t)x1.w;
                tmp[8]=(bf16_t)x2.x; tmp[9]=(bf16_t)x2.y; tmp[10]=(bf16_t)x2.z; tmp[11]=(bf16_t)x2.w;
                tmp[12]=(bf16_t)x3.x; tmp[13]=(bf16_t)x3.y; tmp[14]=(bf16_t)x3.z; tmp[15]=(bf16_t)x3.w;
            } else {
#pragma unroll
                for (int j = 0; j < 16; ++j) tmp[j] = (bf16_t)0.f;
            }
            bf16x8* d = (bf16x8*)&sA[srow * LDK + shalf];
            d[0] = *(bf16x8*)&tmp[0];
            d[1] = *(bf16x8*)&tmp[8];
        }
        {
            const bf16x8* s = (const bf16x8*)(Wt + (size_t)(bn + srow) * wtStride + kOff + k0 + shalf);
            bf16x8* d = (bf16x8*)&sB[srow * LDK + shalf];
            d[0] = s[0];
            d[1] = s[1];
        }
        __syncthreads();
        bf16x8 af[4], bfr[4];
#pragma unroll
        for (int i = 0; i < 4; ++i)
            af[i] = *(bf16x8*)&sA[(wr * 64 + i * 16 + lm) * LDK + kg * 8];
#pragma unroll
        for (int j = 0; j < 4; ++j)
            bfr[j] = *(bf16x8*)&sB[(wc * 64 + j * 16 + lm) * LDK + kg * 8];
#pragma unroll
        for (int i = 0; i < 4; ++i)
#pragma unroll
            for (int j = 0; j < 4; ++j)
                acc[i][j] = __builtin_amdgcn_mfma_f32_16x16x32_bf16(af[i], bfr[j], acc[i][j], 0, 0, 0);
        __syncthreads();
    }

#pragma unroll
    for (int j = 0; j < 4; ++j) {
        const int col = bn + wc * 64 + j * 16 + lm;
        const float bv = bias ? bias[col] : 0.f;
#pragma unroll
        for (int i = 0; i < 4; ++i) {
            const int rbase = bm + wr * 64 + i * 16 + kg * 4;
#pragma unroll
            for (int r = 0; r < 4; ++r) {
                const int rw = rbase + r;
                if (rw < M)
                    C[(size_t)rw * DD + col] = (bf16_t)(acc[i][j][r] + bv);
            }
        }
    }
}

// ---------------- fused weight transposes: Wt[n][k] = (bf16)W[k][n] ----------------
struct WtJobs {
    const float* W[9];
    bf16_t* T[9];
    int KK[9];
};
__global__ __launch_bounds__(256)
void wtall_k(WtJobs jobs)
{
    __shared__ float sh[32][33];
    const int id = blockIdx.z;
    const float* W = jobs.W[id];
    bf16_t* Wt = jobs.T[id];
    const int KK = jobs.KK[id];
    const int k0 = blockIdx.x * 32, n0 = blockIdx.y * 32;
    if (k0 >= KK) return;
    const int tr = threadIdx.x >> 5, tc = threadIdx.x & 31;
#pragma unroll
    for (int it = 0; it < 4; ++it)
        sh[tr + 8 * it][tc] = W[(size_t)(k0 + tr + 8 * it) * DD + n0 + tc];
    __syncthreads();
#pragma unroll
    for (int it = 0; it < 4; ++it)
        Wt[(size_t)(n0 + tr + 8 * it) * KK + k0 + tc] = (bf16_t)sh[tc][tr + 8 * it];
}

// ---------------- CSR build ----------------
__global__ __launch_bounds__(256)
void count_k(const int* __restrict__ src, const int* __restrict__ dst,
             int* __restrict__ cntV, int* __restrict__ cntF)
{
    int e = blockIdx.x * 256 + threadIdx.x;
    if (e < NEDGE) {
        atomicAdd(&cntF[dst[e]], 1);
        atomicAdd(&cntV[src[e]], 1);
    }
}

__global__ __launch_bounds__(256)
void cs1_k(const int* __restrict__ cntF, const int* __restrict__ cntV,
           int* __restrict__ bsumF, int* __restrict__ bsumV)
{
    __shared__ int red[256];
    const int b = blockIdx.x;
    const int* cnt; int n; int* bsum; int bb;
    if (b < NBF) { cnt = cntF; n = NFAC; bsum = bsumF; bb = b; }
    else         { cnt = cntV; n = NVAR; bsum = bsumV; bb = b - NBF; }
    const int t = threadIdx.x;
    const int i = bb * 256 + t;
    red[t] = (i < n) ? cnt[i] : 0;
    __syncthreads();
    for (int s = 128; s > 0; s >>= 1) {
        if (t < s) red[t] += red[t + s];
        __syncthreads();
    }
    if (t == 0) bsum[bb] = red[0];
}

__global__ __launch_bounds__(256)
void cs2_k(int* __restrict__ bsumF, int* __restrict__ bsumV)
{
    int* bsum = blockIdx.x ? bsumV : bsumF;
    const int n = blockIdx.x ? NBV : NBF;
    __shared__ int sh[256];
    const int t = threadIdx.x;
    const int v = (t < n) ? bsum[t] : 0;
    sh[t] = v;
    __syncthreads();
    for (int off = 1; off < 256; off <<= 1) {
        int u = (t >= off) ? sh[t - off] : 0;
        __syncthreads();
        sh[t] += u;
        __syncthreads();
    }
    if (t < n) bsum[t] = sh[t] - v;
}

__global__ __launch_bounds__(256)
void cs3_k(const int* __restrict__ cntF, const int* __restrict__ cntV,
           const int* __restrict__ bsumF, const int* __restrict__ bsumV,
           int* __restrict__ offsF, int* __restrict__ curF,
           int* __restrict__ offsV, int* __restrict__ curV)
{
    __shared__ int sh[256];
    const int b = blockIdx.x;
    const int* cnt; int n; const int* bsum; int bb; int* offs; int* cur;
    if (b < NBF) { cnt = cntF; n = NFAC; bsum = bsumF; bb = b; offs = offsF; cur = curF; }
    else         { cnt = cntV; n = NVAR; bsum = bsumV; bb = b - NBF; offs = offsV; cur = curV; }
    const int t = threadIdx.x;
    const int i = bb * 256 + t;
    const int v = (i < n) ? cnt[i] : 0;
    sh[t] = v;
    __syncthreads();
    for (int off = 1; off < 256; off <<= 1) {
        int u = (t >= off) ? sh[t - off] : 0;
        __syncthreads();
        sh[t] += u;
        __syncthreads();
    }
    const int excl = sh[t] - v + bsum[bb];
    if (i < n) {
        offs[i] = excl; cur[i] = excl;
        if (i == n - 1) offs[n] = excl + v;
    }
}

__global__ __launch_bounds__(256)
void scatter_k(const int* __restrict__ src, const int* __restrict__ dst,
               int* __restrict__ curV, int* __restrict__ curF,
               int* __restrict__ lstV, int* __restrict__ lstF)
{
    int e = blockIdx.x * 256 + threadIdx.x;
    if (e < NEDGE) {
        int s = src[e], d = dst[e];
        int pf = atomicAdd(&curF[d], 1);
        lstF[pf] = s;
        int pv = atomicAdd(&curV[s], 1);
        lstV[pv] = d;
    }
}

// ---------------- gather-aggregate (bf16 in/out, f32 accumulate) ----------------
__global__ __launch_bounds__(256)
void aggb_k(const bf16_t* __restrict__ Pa, const bf16_t* __restrict__ Pb,
            const int* __restrict__ offs, const int* __restrict__ lst,
            bf16_t* __restrict__ agg, int Na)
{
    int a = blockIdx.x * 4 + (threadIdx.x >> 6);
    if (a >= Na) return;
    int lane = threadIdx.x & 63;
    const size_t c = (size_t)lane * 4;
    bf16x4 bv = *(const bf16x4*)(Pa + (size_t)a * DD + c);
    const float b0 = (float)bv[0], b1 = (float)bv[1], b2 = (float)bv[2], b3 = (float)bv[3];
    float s0 = 0.f, s1 = 0.f, s2 = 0.f, s3 = 0.f;
    const int e0 = offs[a], e1 = offs[a + 1];
    for (int e = e0; e < e1; ++e) {
        int b = lst[e];
        bf16x4 x = *(const bf16x4*)(Pb + (size_t)b * DD + c);
        s0 += fmaxf(b0 + (float)x[0], 0.f);
        s1 += fmaxf(b1 + (float)x[1], 0.f);
        s2 += fmaxf(b2 + (float)x[2], 0.f);
        s3 += fmaxf(b3 + (float)x[3], 0.f);
    }
    bf16x4 o;
    o[0] = (bf16_t)s0; o[1] = (bf16_t)s1; o[2] = (bf16_t)s2; o[3] = (bf16_t)s3;
    *(bf16x4*)(agg + (size_t)a * DD + c) = o;
}

// ---------------- global node ----------------
// gate[f] = dot(fac[f], gw) + gb; fused per-graph atomic max (ordered-uint)
__global__ __launch_bounds__(256)
void gate_k(const float* __restrict__ fac, const float* __restrict__ gw,
            const float* __restrict__ gb, const int* __restrict__ batch,
            float* __restrict__ gate, unsigned* __restrict__ mxu)
{
    int f = blockIdx.x * 4 + (threadIdx.x >> 6);
    int lane = threadIdx.x & 63;
    float4 x = *(const float4*)(fac + (size_t)f * DD + lane * 4);
    float4 w = *(const float4*)(gw + lane * 4);
    float s = x.x * w.x + x.y * w.y + x.z * w.z + x.w * w.w;
#pragma unroll
    for (int o = 32; o > 0; o >>= 1) s += __shfl_down(s, o);
    if (lane == 0) {
        float g = s + gb[0];
        gate[f] = g;
        atomicMax(&mxu[batch[f]], encf(g));
    }
}

// den[b] += exp(gate[f] - max[b])
__global__ __launch_bounds__(256)
void gden_k(const float* __restrict__ gate, const int* __restrict__ batch,
            const unsigned* __restrict__ mxu, float* __restrict__ den)
{
    int f = blockIdx.x * 256 + threadIdx.x;
    if (f < NFAC) {
        int b = batch[f];
        atomicAdd(&den[b], __expf(gate[f] - decf(mxu[b])));
    }
}

__global__ __launch_bounds__(256)
void gagg_k(const bf16_t* __restrict__ t, const float* __restrict__ gate,
            const int* __restrict__ batch, const unsigned* __restrict__ mxu,
            const float* __restrict__ den, float* __restrict__ gagg)
{
    int tid = threadIdx.x;
    int f0 = blockIdx.x * 64;
    float a = 0.f;
    int cur = batch[f0];
    for (int f = f0; f < f0 + 64; ++f) {
        int b = batch[f];
        if (b != cur) {
            atomicAdd(&gagg[(size_t)cur * DD + tid], a);
            a = 0.f; cur = b;
        }
        float coef = __expf(gate[f] - decf(mxu[b])) / den[b];
        a += coef * (float)t[(size_t)f * DD + tid];
    }
    atomicAdd(&gagg[(size_t)cur * DD + tid], a);
}

__global__ __launch_bounds__(256)
void gfin_k(const float* __restrict__ gagg, const float* __restrict__ glW,
            const float* __restrict__ glb, float* __restrict__ gout)
{
    int row = blockIdx.x, col = threadIdx.x;
    float s = glb[col];
    for (int k = 0; k < DD; ++k) s += gagg[row * DD + k] * glW[k * DD + col];
    gout[row * DD + col] = fmaxf(s, 0.f);
}

extern "C" void kernel_launch(void* const* d_in, const int* in_sizes, int n_in,
                              void* d_out, int out_size, void* d_ws, size_t ws_size,
                              hipStream_t stream) {
    (void)in_sizes; (void)n_in; (void)out_size; (void)ws_size;
    const float* variables = (const float*)d_in[0];
    const float* factors   = (const float*)d_in[1];
    const int*   edge_index = (const int*)d_in[3];
    const int*   batch      = (const int*)d_in[4];
    const float* mW_v2f = (const float*)d_in[5];
    const float* mb_v2f = (const float*)d_in[6];
    const float* cW_v2f = (const float*)d_in[7];
    const float* cb_v2f = (const float*)d_in[8];
    const float* mW_f2v = (const float*)d_in[9];
    const float* mb_f2v = (const float*)d_in[10];
    const float* cW_f2v = (const float*)d_in[11];
    const float* cb_f2v = (const float*)d_in[12];
    const float* gate_W = (const float*)d_in[13];
    const float* gate_b = (const float*)d_in[14];
    const float* att_W  = (const float*)d_in[15];
    const float* att_b  = (const float*)d_in[16];
    const float* gl_W   = (const float*)d_in[17];
    const float* gl_b   = (const float*)d_in[18];

    const int* src = edge_index;           // row 0: variable idx
    const int* dst = edge_index + NEDGE;   // row 1: factor idx

    float* out = (float*)d_out;
    float* V1 = out;
    float* F1 = out + (size_t)NVAR * DD;
    float* gout = out + (size_t)(NVAR + NFAC) * DD;
    bf16_t* V1b = (bf16_t*)V1;
    bf16_t* F1b = (bf16_t*)F1;

    float* ws  = (float*)d_ws;
    float* F0   = ws;                               // NFAC*DD f32
    float* V0   = F0 + (size_t)NFAC * DD;           // NVAR*DD f32
    bf16_t* AGG = (bf16_t*)(V0 + (size_t)NVAR * DD);// NFAC*DD bf16
    float* gate = (float*)(AGG + (size_t)NFAC * DD);// NFAC
    unsigned* mxu = (unsigned*)(gate + NFAC);       // NGRAPH
    float* den  = (float*)(mxu + NGRAPH);           // NGRAPH
    float* gagg = den + NGRAPH;                     // NGRAPH*DD
    int* ip    = (int*)(gagg + (size_t)NGRAPH * DD);
    int* cntF  = ip;              ip += NFAC;
    int* offsF = ip;              ip += NFAC + 1;
    int* curF  = ip;              ip += NFAC;
    int* lstF  = ip;              ip += NEDGE;
    int* cntV  = ip;              ip += NVAR;
    int* offsV = ip;              ip += NVAR + 1;
    int* curV  = ip;              ip += NVAR;
    int* lstV  = ip;              ip += NEDGE;
    int* bsumF = ip;              ip += NBF;
    int* bsumV = ip;              ip += NBV;
    bf16_t* F0b = (bf16_t*)F0;

    bf16_t* wt = (bf16_t*)(((uintptr_t)ip + 15) & ~(uintptr_t)15);
    bf16_t* WT_mv2f[2]; bf16_t* WT_cv2f[2]; bf16_t* WT_mf2v[2]; bf16_t* WT_cf2v[2];
    size_t woff = 0;
    for (int l = 0; l < 2; ++l) { WT_mv2f[l] = wt + woff; woff += (size_t)DD * 2 * DD; }
    for (int l = 0; l < 2; ++l) { WT_cv2f[l] = wt + woff; woff += (size_t)DD * 2 * DD; }
    for (int l = 0; l < 2; ++l) { WT_mf2v[l] = wt + woff; woff += (size_t)DD * 2 * DD; }
    for (int l = 0; l < 2; ++l) { WT_cf2v[l] = wt + woff; woff += (size_t)DD * 2 * DD; }
    bf16_t* WT_att = wt + woff;

    dim3 blk(256);

    // ---- all 9 weight transposes in one launch
    {
        WtJobs jobs;
        for (int l = 0; l < 2; ++l) {
            jobs.W[l]     = mW_v2f + (size_t)l * 2 * DD * DD; jobs.T[l]     = WT_mv2f[l]; jobs.KK[l]     = 2 * DD;
            jobs.W[2 + l] = cW_v2f + (size_t)l * 2 * DD * DD; jobs.T[2 + l] = WT_cv2f[l]; jobs.KK[2 + l] = 2 * DD;
            jobs.W[4 + l] = mW_f2v + (size_t)l * 2 * DD * DD; jobs.T[4 + l] = WT_mf2v[l]; jobs.KK[4 + l] = 2 * DD;
            jobs.W[6 + l] = cW_f2v + (size_t)l * 2 * DD * DD; jobs.T[6 + l] = WT_cf2v[l]; jobs.KK[6 + l] = 2 * DD;
        }
        jobs.W[8] = att_W; jobs.T[8] = WT_att; jobs.KK[8] = DD;
        wtall_k<<<dim3(2 * DD / 32, DD / 32, 9), blk, 0, stream>>>(jobs);
    }

    // ---- CSR build
    hipMemsetAsync(cntF, 0, NFAC * sizeof(int), stream);
    hipMemsetAsync(cntV, 0, NVAR * sizeof(int), stream);
    count_k<<<dim3((NEDGE + 255) / 256), blk, 0, stream>>>(src, dst, cntV, cntF);
    cs1_k<<<dim3(NBF + NBV), blk, 0, stream>>>(cntF, cntV, bsumF, bsumV);
    cs2_k<<<dim3(2), blk, 0, stream>>>(bsumF, bsumV);
    cs3_k<<<dim3(NBF + NBV), blk, 0, stream>>>(cntF, cntV, bsumF, bsumV, offsF, curF, offsV, curV);
    scatter_k<<<dim3((NEDGE + 255) / 256), blk, 0, stream>>>(src, dst, curV, curF, lstV, lstF);

    const int gxF = (NFAC + GBM - 1) / GBM;   // 313
    const int gxV = (NVAR + GBM - 1) / GBM;   // 157
    dim3 gF2(gxF, DD / GBN);
    dim3 gV2(gxV, DD / GBN);
    dim3 gP(gxF + gxV, DD / GBN);

    // ================= layer 0 =================
    {
        pgemm_k<<<gP, blk, 0, stream>>>(factors, mb_v2f, 0, F1b, NFAC, gxF,
                                        variables, nullptr, DD, V1b, NVAR,
                                        WT_mv2f[0], 2 * DD);
        aggb_k<<<dim3(NFAC / 4), blk, 0, stream>>>(F1b, V1b, offsF, lstF, AGG, NFAC);
        mgemm_k<true,true,false,true,false><<<gF2, blk, 0, stream>>>(factors, AGG, WT_cv2f[0], 2*DD, 0, DD, cb_v2f, nullptr, F0, NFAC);
        pgemm_k<<<gP, blk, 0, stream>>>(F0, nullptr, DD, F1b, NFAC, gxF,
                                        variables, mb_f2v, 0, V1b, NVAR,
                                        WT_mf2v[0], 2 * DD);
        aggb_k<<<dim3(NVAR / 4), blk, 0, stream>>>(V1b, F1b, offsV, lstV, AGG, NVAR);
        mgemm_k<true,true,true,true,false><<<gV2, blk, 0, stream>>>(variables, AGG, WT_cf2v[0], 2*DD, 0, DD, cb_f2v, variables, V0, NVAR);
    }
    // ================= layer 1 =================
    {
        pgemm_k<<<gP, blk, 0, stream>>>(F0, mb_v2f + DD, 0, F1b, NFAC, gxF,
                                        V0, nullptr, DD, V1b, NVAR,
                                        WT_mv2f[1], 2 * DD);
        aggb_k<<<dim3(NFAC / 4), blk, 0, stream>>>(F1b, V1b, offsF, lstF, AGG, NFAC);
        mgemm_k<true,true,false,true,false><<<gF2, blk, 0, stream>>>(F0, AGG, WT_cv2f[1], 2*DD, 0, DD, cb_v2f + DD, nullptr, F1, NFAC);  // fac2 -> d_out
        pgemm_k<<<gP, blk, 0, stream>>>(F1, nullptr, DD, F0b, NFAC, gxF,
                                        V0, mb_f2v + DD, 0, V1b, NVAR,
                                        WT_mf2v[1], 2 * DD);
        aggb_k<<<dim3(NVAR / 4), blk, 0, stream>>>(V1b, F0b, offsV, lstV, AGG, NVAR);
        mgemm_k<true,true,true,true,false><<<gV2, blk, 0, stream>>>(V0, AGG, WT_cf2v[1], 2*DD, 0, DD, cb_f2v + DD, V0, V1, NVAR);        // var2 -> d_out
    }

    // ================= global node =================
    hipMemsetAsync(mxu, 0, NGRAPH * sizeof(unsigned), stream);
    hipMemsetAsync(den, 0, NGRAPH * sizeof(float), stream);
    gate_k<<<dim3(NFAC / 4), blk, 0, stream>>>(F1, gate_W, gate_b, batch, gate, mxu);
    gden_k<<<dim3(NBF), blk, 0, stream>>>(gate, batch, mxu, den);
    mgemm_k<false,false,false,false,true><<<gF2, blk, 0, stream>>>(F1, nullptr, WT_att, DD, 0, 0, att_b, nullptr, F0b, NFAC);
    hipMemsetAsync(gagg, 0, (size_t)NGRAPH * DD * sizeof(float), stream);
    gagg_k<<<dim3(NFAC / 64), blk, 0, stream>>>(F0b, gate, batch, mxu, den, gagg);
    gfin_k<<<dim3(NGRAPH), blk, 0, stream>>>(gagg, gl_W, gl_b, gout);
}

// Round 12
// 796.325 us; speedup vs baseline: 1.6223x; 1.6223x over previous
//
#include <hip/hip_runtime.h>

#define DD 256
#define NVAR 20000
#define NFAC 40000
#define NEDGE 320000
#define NGRAPH 64
#define GPAD 32   // one 128-B cache line per graph for atomic stats

#define NBF ((NFAC + 255) / 256)   // 157
#define NBV ((NVAR + 255) / 256)   // 79

typedef __bf16 bf16_t;
typedef bf16_t bf16x8 __attribute__((ext_vector_type(8)));
typedef bf16_t bf16x4 __attribute__((ext_vector_type(4)));
typedef float f32x4 __attribute__((ext_vector_type(4)));

#define GBM 128
#define GBN 128
#define GBK 32
#define LDK 40   // padded k-stride (bf16 elems) for LDS tiles

// ordered-uint encoding of float for atomicMax (monotone). memset-0 acts as -inf.
__device__ __forceinline__ unsigned encf(float f) {
    int i = __float_as_int(f);
    return (i >= 0) ? ((unsigned)i + 0x80000000u) : (unsigned)(~i);
}
__device__ __forceinline__ float decf(unsigned u) {
    int i = (u >= 0x80000000u) ? (int)(u - 0x80000000u) : ~(int)u;
    return __int_as_float(i);
}

// ---------------- MFMA GEMM (combine / att) ----------------
template<bool RELU, bool HASA2, bool HASRES, bool A2BF, bool OUTBF>
__global__ __launch_bounds__(256)
void mgemm_k(const float* __restrict__ A1, const void* __restrict__ A2v,
             const bf16_t* __restrict__ Wt, int wtStride, int kOff1, int kOff2,
             const float* __restrict__ bias, const float* __restrict__ res,
             void* __restrict__ Cv, int M)
{
    __shared__ bf16_t sA[GBM * LDK];
    __shared__ bf16_t sB[GBN * LDK];

    const int tid = threadIdx.x;
    const int bm = blockIdx.x * GBM;
    const int bn = blockIdx.y * GBN;

    const int w  = tid >> 6;
    const int l  = tid & 63;
    const int wr = w >> 1;
    const int wc = w & 1;
    const int lm = l & 15;
    const int kg = l >> 4;

    const int srow = tid >> 1;
    const int shalf = (tid & 1) * 16;

    f32x4 acc[4][4];
#pragma unroll
    for (int i = 0; i < 4; ++i)
#pragma unroll
        for (int j = 0; j < 4; ++j) acc[i][j] = (f32x4)0.f;

    const int nops = HASA2 ? 2 : 1;
    for (int op = 0; op < nops; ++op) {
        const int kOff = op ? kOff2 : kOff1;
        for (int k0 = 0; k0 < DD; k0 += GBK) {
            {
                const int grow = bm + srow;
                bf16x8* d = (bf16x8*)&sA[srow * LDK + shalf];
                if (op == 1 && A2BF) {
                    const bf16_t* A2b = (const bf16_t*)A2v;
                    if (grow < M) {
                        const bf16x8* s = (const bf16x8*)(A2b + (size_t)grow * DD + k0 + shalf);
                        d[0] = s[0]; d[1] = s[1];
                    } else {
                        d[0] = (bf16x8)(bf16_t)0.f; d[1] = (bf16x8)(bf16_t)0.f;
                    }
                } else {
                    const float* Aop = op ? (const float*)A2v : A1;
                    bf16_t tmp[16];
                    if (grow < M) {
                        const float4* p = (const float4*)(Aop + (size_t)grow * DD + k0 + shalf);
                        float4 x0 = p[0], x1 = p[1], x2 = p[2], x3 = p[3];
                        tmp[0]=(bf16_t)x0.x; tmp[1]=(bf16_t)x0.y; tmp[2]=(bf16_t)x0.z; tmp[3]=(bf16_t)x0.w;
                        tmp[4]=(bf16_t)x1.x; tmp[5]=(bf16_t)x1.y; tmp[6]=(bf16_t)x1.z; tmp[7]=(bf16_t)x1.w;
                        tmp[8]=(bf16_t)x2.x; tmp[9]=(bf16_t)x2.y; tmp[10]=(bf16_t)x2.z; tmp[11]=(bf16_t)x2.w;
                        tmp[12]=(bf16_t)x3.x; tmp[13]=(bf16_t)x3.y; tmp[14]=(bf16_t)x3.z; tmp[15]=(bf16_t)x3.w;
                    } else {
#pragma unroll
                        for (int j = 0; j < 16; ++j) tmp[j] = (bf16_t)0.f;
                    }
                    d[0] = *(bf16x8*)&tmp[0];
                    d[1] = *(bf16x8*)&tmp[8];
                }
            }
            {
                const bf16x8* s = (const bf16x8*)(Wt + (size_t)(bn + srow) * wtStride + kOff + k0 + shalf);
                bf16x8* d = (bf16x8*)&sB[srow * LDK + shalf];
                d[0] = s[0];
                d[1] = s[1];
            }
            __syncthreads();
            bf16x8 af[4], bfr[4];
#pragma unroll
            for (int i = 0; i < 4; ++i)
                af[i] = *(bf16x8*)&sA[(wr * 64 + i * 16 + lm) * LDK + kg * 8];
#pragma unroll
            for (int j = 0; j < 4; ++j)
                bfr[j] = *(bf16x8*)&sB[(wc * 64 + j * 16 + lm) * LDK + kg * 8];
#pragma unroll
            for (int i = 0; i < 4; ++i)
#pragma unroll
                for (int j = 0; j < 4; ++j)
                    acc[i][j] = __builtin_amdgcn_mfma_f32_16x16x32_bf16(af[i], bfr[j], acc[i][j], 0, 0, 0);
            __syncthreads();
        }
    }

#pragma unroll
    for (int j = 0; j < 4; ++j) {
        const int col = bn + wc * 64 + j * 16 + lm;
        const float bv = bias ? bias[col] : 0.f;
#pragma unroll
        for (int i = 0; i < 4; ++i) {
            const int rbase = bm + wr * 64 + i * 16 + kg * 4;
#pragma unroll
            for (int r = 0; r < 4; ++r) {
                const int rw = rbase + r;
                if (rw < M) {
                    float v = acc[i][j][r] + bv;
                    if (RELU) v = fmaxf(v, 0.f);
                    if (HASRES) v += res[(size_t)rw * DD + col];
                    if (OUTBF) ((bf16_t*)Cv)[(size_t)rw * DD + col] = (bf16_t)v;
                    else       ((float*)Cv)[(size_t)rw * DD + col] = v;
                }
            }
        }
    }
}

// ---------------- dual P-GEMM: two independent M-row sets, same Wt, bf16 out ----------------
__global__ __launch_bounds__(256)
void pgemm_k(const float* __restrict__ Aa, const float* __restrict__ biasA, int kOffA,
             bf16_t* __restrict__ Ca, int Ma, int gridXA,
             const float* __restrict__ Ab, const float* __restrict__ biasB, int kOffB,
             bf16_t* __restrict__ Cb, int Mb,
             const bf16_t* __restrict__ Wt, int wtStride)
{
    __shared__ bf16_t sA[GBM * LDK];
    __shared__ bf16_t sB[GBN * LDK];

    const int tid = threadIdx.x;
    const bool partB = (int)blockIdx.x >= gridXA;
    const int bx = partB ? (blockIdx.x - gridXA) : blockIdx.x;
    const float* A = partB ? Ab : Aa;
    const float* bias = partB ? biasB : biasA;
    const int kOff = partB ? kOffB : kOffA;
    bf16_t* C = partB ? Cb : Ca;
    const int M = partB ? Mb : Ma;

    const int bm = bx * GBM;
    const int bn = blockIdx.y * GBN;

    const int w  = tid >> 6;
    const int l  = tid & 63;
    const int wr = w >> 1;
    const int wc = w & 1;
    const int lm = l & 15;
    const int kg = l >> 4;

    const int srow = tid >> 1;
    const int shalf = (tid & 1) * 16;

    f32x4 acc[4][4];
#pragma unroll
    for (int i = 0; i < 4; ++i)
#pragma unroll
        for (int j = 0; j < 4; ++j) acc[i][j] = (f32x4)0.f;

    for (int k0 = 0; k0 < DD; k0 += GBK) {
        {
            const int grow = bm + srow;
            bf16_t tmp[16];
            if (grow < M) {
                const float4* p = (const float4*)(A + (size_t)grow * DD + k0 + shalf);
                float4 x0 = p[0], x1 = p[1], x2 = p[2], x3 = p[3];
                tmp[0]=(bf16_t)x0.x; tmp[1]=(bf16_t)x0.y; tmp[2]=(bf16_t)x0.z; tmp[3]=(bf16_t)x0.w;
                tmp[4]=(bf16_t)x1.x; tmp[5]=(bf16_t)x1.y; tmp[6]=(bf16_t)x1.z; tmp[7]=(bf16_t)x1.w;
                tmp[8]=(bf16_t)x2.x; tmp[9]=(bf16_t)x2.y; tmp[10]=(bf16_t)x2.z; tmp[11]=(bf16_t)x2.w;
                tmp[12]=(bf16_t)x3.x; tmp[13]=(bf16_t)x3.y; tmp[14]=(bf16_t)x3.z; tmp[15]=(bf16_t)x3.w;
            } else {
#pragma unroll
                for (int j = 0; j < 16; ++j) tmp[j] = (bf16_t)0.f;
            }
            bf16x8* d = (bf16x8*)&sA[srow * LDK + shalf];
            d[0] = *(bf16x8*)&tmp[0];
            d[1] = *(bf16x8*)&tmp[8];
        }
        {
            const bf16x8* s = (const bf16x8*)(Wt + (size_t)(bn + srow) * wtStride + kOff + k0 + shalf);
            bf16x8* d = (bf16x8*)&sB[srow * LDK + shalf];
            d[0] = s[0];
            d[1] = s[1];
        }
        __syncthreads();
        bf16x8 af[4], bfr[4];
#pragma unroll
        for (int i = 0; i < 4; ++i)
            af[i] = *(bf16x8*)&sA[(wr * 64 + i * 16 + lm) * LDK + kg * 8];
#pragma unroll
        for (int j = 0; j < 4; ++j)
            bfr[j] = *(bf16x8*)&sB[(wc * 64 + j * 16 + lm) * LDK + kg * 8];
#pragma unroll
        for (int i = 0; i < 4; ++i)
#pragma unroll
            for (int j = 0; j < 4; ++j)
                acc[i][j] = __builtin_amdgcn_mfma_f32_16x16x32_bf16(af[i], bfr[j], acc[i][j], 0, 0, 0);
        __syncthreads();
    }

#pragma unroll
    for (int j = 0; j < 4; ++j) {
        const int col = bn + wc * 64 + j * 16 + lm;
        const float bv = bias ? bias[col] : 0.f;
#pragma unroll
        for (int i = 0; i < 4; ++i) {
            const int rbase = bm + wr * 64 + i * 16 + kg * 4;
#pragma unroll
            for (int r = 0; r < 4; ++r) {
                const int rw = rbase + r;
                if (rw < M)
                    C[(size_t)rw * DD + col] = (bf16_t)(acc[i][j][r] + bv);
            }
        }
    }
}

// ---------------- fused weight transposes: Wt[n][k] = (bf16)W[k][n] ----------------
struct WtJobs {
    const float* W[9];
    bf16_t* T[9];
    int KK[9];
};
__global__ __launch_bounds__(256)
void wtall_k(WtJobs jobs)
{
    __shared__ float sh[32][33];
    const int id = blockIdx.z;
    const float* W = jobs.W[id];
    bf16_t* Wt = jobs.T[id];
    const int KK = jobs.KK[id];
    const int k0 = blockIdx.x * 32, n0 = blockIdx.y * 32;
    if (k0 >= KK) return;
    const int tr = threadIdx.x >> 5, tc = threadIdx.x & 31;
#pragma unroll
    for (int it = 0; it < 4; ++it)
        sh[tr + 8 * it][tc] = W[(size_t)(k0 + tr + 8 * it) * DD + n0 + tc];
    __syncthreads();
#pragma unroll
    for (int it = 0; it < 4; ++it)
        Wt[(size_t)(n0 + tr + 8 * it) * KK + k0 + tc] = (bf16_t)sh[tc][tr + 8 * it];
}

// ---------------- CSR build ----------------
__global__ __launch_bounds__(256)
void count_k(const int* __restrict__ src, const int* __restrict__ dst,
             int* __restrict__ cntV, int* __restrict__ cntF)
{
    int e = blockIdx.x * 256 + threadIdx.x;
    if (e < NEDGE) {
        atomicAdd(&cntF[dst[e]], 1);
        atomicAdd(&cntV[src[e]], 1);
    }
}

__global__ __launch_bounds__(256)
void cs1_k(const int* __restrict__ cntF, const int* __restrict__ cntV,
           int* __restrict__ bsumF, int* __restrict__ bsumV)
{
    __shared__ int red[256];
    const int b = blockIdx.x;
    const int* cnt; int n; int* bsum; int bb;
    if (b < NBF) { cnt = cntF; n = NFAC; bsum = bsumF; bb = b; }
    else         { cnt = cntV; n = NVAR; bsum = bsumV; bb = b - NBF; }
    const int t = threadIdx.x;
    const int i = bb * 256 + t;
    red[t] = (i < n) ? cnt[i] : 0;
    __syncthreads();
    for (int s = 128; s > 0; s >>= 1) {
        if (t < s) red[t] += red[t + s];
        __syncthreads();
    }
    if (t == 0) bsum[bb] = red[0];
}

__global__ __launch_bounds__(256)
void cs2_k(int* __restrict__ bsumF, int* __restrict__ bsumV)
{
    int* bsum = blockIdx.x ? bsumV : bsumF;
    const int n = blockIdx.x ? NBV : NBF;
    __shared__ int sh[256];
    const int t = threadIdx.x;
    const int v = (t < n) ? bsum[t] : 0;
    sh[t] = v;
    __syncthreads();
    for (int off = 1; off < 256; off <<= 1) {
        int u = (t >= off) ? sh[t - off] : 0;
        __syncthreads();
        sh[t] += u;
        __syncthreads();
    }
    if (t < n) bsum[t] = sh[t] - v;
}

__global__ __launch_bounds__(256)
void cs3_k(const int* __restrict__ cntF, const int* __restrict__ cntV,
           const int* __restrict__ bsumF, const int* __restrict__ bsumV,
           int* __restrict__ offsF, int* __restrict__ curF,
           int* __restrict__ offsV, int* __restrict__ curV)
{
    __shared__ int sh[256];
    const int b = blockIdx.x;
    const int* cnt; int n; const int* bsum; int bb; int* offs; int* cur;
    if (b < NBF) { cnt = cntF; n = NFAC; bsum = bsumF; bb = b; offs = offsF; cur = curF; }
    else         { cnt = cntV; n = NVAR; bsum = bsumV; bb = b - NBF; offs = offsV; cur = curV; }
    const int t = threadIdx.x;
    const int i = bb * 256 + t;
    const int v = (i < n) ? cnt[i] : 0;
    sh[t] = v;
    __syncthreads();
    for (int off = 1; off < 256; off <<= 1) {
        int u = (t >= off) ? sh[t - off] : 0;
        __syncthreads();
        sh[t] += u;
        __syncthreads();
    }
    const int excl = sh[t] - v + bsum[bb];
    if (i < n) {
        offs[i] = excl; cur[i] = excl;
        if (i == n - 1) offs[n] = excl + v;
    }
}

__global__ __launch_bounds__(256)
void scatter_k(const int* __restrict__ src, const int* __restrict__ dst,
               int* __restrict__ curV, int* __restrict__ curF,
               int* __restrict__ lstV, int* __restrict__ lstF)
{
    int e = blockIdx.x * 256 + threadIdx.x;
    if (e < NEDGE) {
        int s = src[e], d = dst[e];
        int pf = atomicAdd(&curF[d], 1);
        lstF[pf] = s;
        int pv = atomicAdd(&curV[s], 1);
        lstV[pv] = d;
    }
}

// ---------------- gather-aggregate (bf16 in/out, f32 accumulate) ----------------
__global__ __launch_bounds__(256)
void aggb_k(const bf16_t* __restrict__ Pa, const bf16_t* __restrict__ Pb,
            const int* __restrict__ offs, const int* __restrict__ lst,
            bf16_t* __restrict__ agg, int Na)
{
    int a = blockIdx.x * 4 + (threadIdx.x >> 6);
    if (a >= Na) return;
    int lane = threadIdx.x & 63;
    const size_t c = (size_t)lane * 4;
    bf16x4 bv = *(const bf16x4*)(Pa + (size_t)a * DD + c);
    const float b0 = (float)bv[0], b1 = (float)bv[1], b2 = (float)bv[2], b3 = (float)bv[3];
    float s0 = 0.f, s1 = 0.f, s2 = 0.f, s3 = 0.f;
    const int e0 = offs[a], e1 = offs[a + 1];
    for (int e = e0; e < e1; ++e) {
        int b = lst[e];
        bf16x4 x = *(const bf16x4*)(Pb + (size_t)b * DD + c);
        s0 += fmaxf(b0 + (float)x[0], 0.f);
        s1 += fmaxf(b1 + (float)x[1], 0.f);
        s2 += fmaxf(b2 + (float)x[2], 0.f);
        s3 += fmaxf(b3 + (float)x[3], 0.f);
    }
    bf16x4 o;
    o[0] = (bf16_t)s0; o[1] = (bf16_t)s1; o[2] = (bf16_t)s2; o[3] = (bf16_t)s3;
    *(bf16x4*)(agg + (size_t)a * DD + c) = o;
}

// ---------------- global node ----------------
// gate[f] = dot(fac[f], gw) + gb   (pure compute, no atomics)
__global__ __launch_bounds__(256)
void gate_k(const float* __restrict__ fac, const float* __restrict__ gw,
            const float* __restrict__ gb, float* __restrict__ gate)
{
    int f = blockIdx.x * 4 + (threadIdx.x >> 6);
    int lane = threadIdx.x & 63;
    float4 x = *(const float4*)(fac + (size_t)f * DD + lane * 4);
    float4 w = *(const float4*)(gw + lane * 4);
    float s = x.x * w.x + x.y * w.y + x.z * w.z + x.w * w.w;
#pragma unroll
    for (int o = 32; o > 0; o >>= 1) s += __shfl_down(s, o);
    if (lane == 0) gate[f] = s + gb[0];
}

// per-block masked reduction over the (<=2) graph runs in 256 sorted factors,
// one atomic per run. mxu padded: one cache line per graph.
__global__ __launch_bounds__(256)
void gmax_k(const float* __restrict__ gate, const int* __restrict__ batch,
            unsigned* __restrict__ mxu)
{
    __shared__ float red[256];
    __shared__ int bb[2];
    const int t = threadIdx.x;
    const int i = blockIdx.x * 256 + t;
    const int idx = (i < NFAC) ? i : NFAC - 1;
    const float v = gate[idx];
    const int b = batch[idx];
    if (t == 0) bb[0] = b;
    if (t == 255) bb[1] = b;
    __syncthreads();
    for (int g = bb[0]; g <= bb[1]; ++g) {
        red[t] = (b == g && i < NFAC) ? v : -1e30f;
        __syncthreads();
        for (int s = 128; s > 0; s >>= 1) {
            if (t < s) red[t] = fmaxf(red[t], red[t + s]);
            __syncthreads();
        }
        if (t == 0) atomicMax(&mxu[g * GPAD], encf(red[0]));
        __syncthreads();
    }
}

__global__ __launch_bounds__(256)
void gden_k(const float* __restrict__ gate, const int* __restrict__ batch,
            const unsigned* __restrict__ mxu, float* __restrict__ den)
{
    __shared__ float red[256];
    __shared__ int bb[2];
    const int t = threadIdx.x;
    const int i = blockIdx.x * 256 + t;
    const int idx = (i < NFAC) ? i : NFAC - 1;
    const float v = gate[idx];
    const int b = batch[idx];
    if (t == 0) bb[0] = b;
    if (t == 255) bb[1] = b;
    __syncthreads();
    for (int g = bb[0]; g <= bb[1]; ++g) {
        red[t] = (b == g && i < NFAC) ? __expf(v - decf(mxu[g * GPAD])) : 0.f;
        __syncthreads();
        for (int s = 128; s > 0; s >>= 1) {
            if (t < s) red[t] += red[t + s];
            __syncthreads();
        }
        if (t == 0) atomicAdd(&den[g * GPAD], red[0]);
        __syncthreads();
    }
}

__global__ __launch_bounds__(256)
void gagg_k(const bf16_t* __restrict__ t, const float* __restrict__ gate,
            const int* __restrict__ batch, const unsigned* __restrict__ mxu,
            const float* __restrict__ den, float* __restrict__ gagg)
{
    int tid = threadIdx.x;
    int f0 = blockIdx.x * 64;
    float a = 0.f;
    int cur = batch[f0];
    for (int f = f0; f < f0 + 64; ++f) {
        int b = batch[f];
        if (b != cur) {
            atomicAdd(&gagg[(size_t)cur * DD + tid], a);
            a = 0.f; cur = b;
        }
        float coef = __expf(gate[f] - decf(mxu[b * GPAD])) / den[b * GPAD];
        a += coef * (float)t[(size_t)f * DD + tid];
    }
    atomicAdd(&gagg[(size_t)cur * DD + tid], a);
}

__global__ __launch_bounds__(256)
void gfin_k(const float* __restrict__ gagg, const float* __restrict__ glW,
            const float* __restrict__ glb, float* __restrict__ gout)
{
    int row = blockIdx.x, col = threadIdx.x;
    float s = glb[col];
    for (int k = 0; k < DD; ++k) s += gagg[row * DD + k] * glW[k * DD + col];
    gout[row * DD + col] = fmaxf(s, 0.f);
}

extern "C" void kernel_launch(void* const* d_in, const int* in_sizes, int n_in,
                              void* d_out, int out_size, void* d_ws, size_t ws_size,
                              hipStream_t stream) {
    (void)in_sizes; (void)n_in; (void)out_size; (void)ws_size;
    const float* variables = (const float*)d_in[0];
    const float* factors   = (const float*)d_in[1];
    const int*   edge_index = (const int*)d_in[3];
    const int*   batch      = (const int*)d_in[4];
    const float* mW_v2f = (const float*)d_in[5];
    const float* mb_v2f = (const float*)d_in[6];
    const float* cW_v2f = (const float*)d_in[7];
    const float* cb_v2f = (const float*)d_in[8];
    const float* mW_f2v = (const float*)d_in[9];
    const float* mb_f2v = (const float*)d_in[10];
    const float* cW_f2v = (const float*)d_in[11];
    const float* cb_f2v = (const float*)d_in[12];
    const float* gate_W = (const float*)d_in[13];
    const float* gate_b = (const float*)d_in[14];
    const float* att_W  = (const float*)d_in[15];
    const float* att_b  = (const float*)d_in[16];
    const float* gl_W   = (const float*)d_in[17];
    const float* gl_b   = (const float*)d_in[18];

    const int* src = edge_index;           // row 0: variable idx
    const int* dst = edge_index + NEDGE;   // row 1: factor idx

    float* out = (float*)d_out;
    float* V1 = out;
    float* F1 = out + (size_t)NVAR * DD;
    float* gout = out + (size_t)(NVAR + NFAC) * DD;
    bf16_t* V1b = (bf16_t*)V1;
    bf16_t* F1b = (bf16_t*)F1;

    float* ws  = (float*)d_ws;
    float* F0   = ws;                               // NFAC*DD f32
    float* V0   = F0 + (size_t)NFAC * DD;           // NVAR*DD f32
    bf16_t* AGG = (bf16_t*)(V0 + (size_t)NVAR * DD);// NFAC*DD bf16
    float* gate = (float*)(AGG + (size_t)NFAC * DD);// NFAC
    unsigned* mxu = (unsigned*)(gate + NFAC);       // NGRAPH*GPAD
    float* den  = (float*)(mxu + NGRAPH * GPAD);    // NGRAPH*GPAD
    float* gagg = den + NGRAPH * GPAD;              // NGRAPH*DD
    int* ip    = (int*)(gagg + (size_t)NGRAPH * DD);
    int* cntF  = ip;              ip += NFAC;
    int* offsF = ip;              ip += NFAC + 1;
    int* curF  = ip;              ip += NFAC;
    int* lstF  = ip;              ip += NEDGE;
    int* cntV  = ip;              ip += NVAR;
    int* offsV = ip;              ip += NVAR + 1;
    int* curV  = ip;              ip += NVAR;
    int* lstV  = ip;              ip += NEDGE;
    int* bsumF = ip;              ip += NBF;
    int* bsumV = ip;              ip += NBV;
    bf16_t* F0b = (bf16_t*)F0;

    bf16_t* wt = (bf16_t*)(((uintptr_t)ip + 15) & ~(uintptr_t)15);
    bf16_t* WT_mv2f[2]; bf16_t* WT_cv2f[2]; bf16_t* WT_mf2v[2]; bf16_t* WT_cf2v[2];
    size_t woff = 0;
    for (int l = 0; l < 2; ++l) { WT_mv2f[l] = wt + woff; woff += (size_t)DD * 2 * DD; }
    for (int l = 0; l < 2; ++l) { WT_cv2f[l] = wt + woff; woff += (size_t)DD * 2 * DD; }
    for (int l = 0; l < 2; ++l) { WT_mf2v[l] = wt + woff; woff += (size_t)DD * 2 * DD; }
    for (int l = 0; l < 2; ++l) { WT_cf2v[l] = wt + woff; woff += (size_t)DD * 2 * DD; }
    bf16_t* WT_att = wt + woff;

    dim3 blk(256);

    // ---- all 9 weight transposes in one launch
    {
        WtJobs jobs;
        for (int l = 0; l < 2; ++l) {
            jobs.W[l]     = mW_v2f + (size_t)l * 2 * DD * DD; jobs.T[l]     = WT_mv2f[l]; jobs.KK[l]     = 2 * DD;
            jobs.W[2 + l] = cW_v2f + (size_t)l * 2 * DD * DD; jobs.T[2 + l] = WT_cv2f[l]; jobs.KK[2 + l] = 2 * DD;
            jobs.W[4 + l] = mW_f2v + (size_t)l * 2 * DD * DD; jobs.T[4 + l] = WT_mf2v[l]; jobs.KK[4 + l] = 2 * DD;
            jobs.W[6 + l] = cW_f2v + (size_t)l * 2 * DD * DD; jobs.T[6 + l] = WT_cf2v[l]; jobs.KK[6 + l] = 2 * DD;
        }
        jobs.W[8] = att_W; jobs.T[8] = WT_att; jobs.KK[8] = DD;
        wtall_k<<<dim3(2 * DD / 32, DD / 32, 9), blk, 0, stream>>>(jobs);
    }

    // ---- CSR build
    hipMemsetAsync(cntF, 0, NFAC * sizeof(int), stream);
    hipMemsetAsync(cntV, 0, NVAR * sizeof(int), stream);
    count_k<<<dim3((NEDGE + 255) / 256), blk, 0, stream>>>(src, dst, cntV, cntF);
    cs1_k<<<dim3(NBF + NBV), blk, 0, stream>>>(cntF, cntV, bsumF, bsumV);
    cs2_k<<<dim3(2), blk, 0, stream>>>(bsumF, bsumV);
    cs3_k<<<dim3(NBF + NBV), blk, 0, stream>>>(cntF, cntV, bsumF, bsumV, offsF, curF, offsV, curV);
    scatter_k<<<dim3((NEDGE + 255) / 256), blk, 0, stream>>>(src, dst, curV, curF, lstV, lstF);

    const int gxF = (NFAC + GBM - 1) / GBM;   // 313
    const int gxV = (NVAR + GBM - 1) / GBM;   // 157
    dim3 gF2(gxF, DD / GBN);
    dim3 gV2(gxV, DD / GBN);
    dim3 gP(gxF + gxV, DD / GBN);

    // ================= layer 0 =================
    {
        pgemm_k<<<gP, blk, 0, stream>>>(factors, mb_v2f, 0, F1b, NFAC, gxF,
                                        variables, nullptr, DD, V1b, NVAR,
                                        WT_mv2f[0], 2 * DD);
        aggb_k<<<dim3(NFAC / 4), blk, 0, stream>>>(F1b, V1b, offsF, lstF, AGG, NFAC);
        mgemm_k<true,true,false,true,false><<<gF2, blk, 0, stream>>>(factors, AGG, WT_cv2f[0], 2*DD, 0, DD, cb_v2f, nullptr, F0, NFAC);
        pgemm_k<<<gP, blk, 0, stream>>>(F0, nullptr, DD, F1b, NFAC, gxF,
                                        variables, mb_f2v, 0, V1b, NVAR,
                                        WT_mf2v[0], 2 * DD);
        aggb_k<<<dim3(NVAR / 4), blk, 0, stream>>>(V1b, F1b, offsV, lstV, AGG, NVAR);
        mgemm_k<true,true,true,true,false><<<gV2, blk, 0, stream>>>(variables, AGG, WT_cf2v[0], 2*DD, 0, DD, cb_f2v, variables, V0, NVAR);
    }
    // ================= layer 1 =================
    {
        pgemm_k<<<gP, blk, 0, stream>>>(F0, mb_v2f + DD, 0, F1b, NFAC, gxF,
                                        V0, nullptr, DD, V1b, NVAR,
                                        WT_mv2f[1], 2 * DD);
        aggb_k<<<dim3(NFAC / 4), blk, 0, stream>>>(F1b, V1b, offsF, lstF, AGG, NFAC);
        mgemm_k<true,true,false,true,false><<<gF2, blk, 0, stream>>>(F0, AGG, WT_cv2f[1], 2*DD, 0, DD, cb_v2f + DD, nullptr, F1, NFAC);  // fac2 -> d_out
        pgemm_k<<<gP, blk, 0, stream>>>(F1, nullptr, DD, F0b, NFAC, gxF,
                                        V0, mb_f2v + DD, 0, V1b, NVAR,
                                        WT_mf2v[1], 2 * DD);
        aggb_k<<<dim3(NVAR / 4), blk, 0, stream>>>(V1b, F0b, offsV, lstV, AGG, NVAR);
        mgemm_k<true,true,true,true,false><<<gV2, blk, 0, stream>>>(V0, AGG, WT_cf2v[1], 2*DD, 0, DD, cb_f2v + DD, V0, V1, NVAR);        // var2 -> d_out
    }

    // ================= global node =================
    hipMemsetAsync(mxu, 0, NGRAPH * GPAD * sizeof(unsigned), stream);
    hipMemsetAsync(den, 0, NGRAPH * GPAD * sizeof(float), stream);
    gate_k<<<dim3(NFAC / 4), blk, 0, stream>>>(F1, gate_W, gate_b, gate);
    gmax_k<<<dim3(NBF), blk, 0, stream>>>(gate, batch, mxu);
    gden_k<<<dim3(NBF), blk, 0, stream>>>(gate, batch, mxu, den);
    mgemm_k<false,false,false,false,true><<<gF2, blk, 0, stream>>>(F1, nullptr, WT_att, DD, 0, 0, att_b, nullptr, F0b, NFAC);
    hipMemsetAsync(gagg, 0, (size_t)NGRAPH * DD * sizeof(float), stream);
    gagg_k<<<dim3(NFAC / 64), blk, 0, stream>>>(F0b, gate, batch, mxu, den, gagg);
    gfin_k<<<dim3(NGRAPH), blk, 0, stream>>>(gagg, gl_W, gl_b, gout);
}